// Round 10
// baseline (541.961 us; speedup 1.0000x reference)
//
#include <hip/hip_runtime.h>
#include <hip/hip_bf16.h>
#include <math.h>

// Round 10: fix the weight path, not the x path.
//  r7-r9 plateau (VALUBusy 36-40% regardless of VALU scheduling) => stall is
//  the scalar K$ (16KB) thrashed by 26KB/wave of s_load weights + 50KB
//  straight-line phase A exceeding the 32KB I$.
//  Fix: L1 (70% of FLOPs) in TRANSPOSE layout -- x LDS-staged in 5 coalesced
//  K-chunks, weights as per-lane float4 VECTOR loads (h_w1 17.9KB lives in
//  32KB vector L1, shared by all waves), compact rolled chunk loop (~1KB
//  code). h1 -> bf16 LDS round-trip -> row-per-lane L2/L3/uv (remaining
//  SGPR weights = 8KB < 16KB K$, no thrash). Phases C-F unchanged.

#define THREADS 256
#define SPB 25
#define NB 65536

__device__ __forceinline__ unsigned bfr(float f) {
    unsigned u = __float_as_uint(f);
    return (u + 0x7fffu + ((u >> 16) & 1u)) >> 16;   // RNE to bf16
}
__device__ __forceinline__ unsigned pack_bf(float a, float b) {
    return bfr(a) | (bfr(b) << 16);
}
__device__ __forceinline__ float bf_lo(unsigned u) { return __uint_as_float(u << 16); }
__device__ __forceinline__ float bf_hi(unsigned u) { return __uint_as_float(u & 0xffff0000u); }

__global__ __launch_bounds__(THREADS, 4) void fused_model_kernel(
    const float* __restrict__ x,
    const float* __restrict__ h_w1, const float* __restrict__ h_b1,
    const float* __restrict__ h_w2, const float* __restrict__ h_b2,
    const float* __restrict__ h_w3, const float* __restrict__ h_b3,
    const float* __restrict__ c_w1, const float* __restrict__ c_b1,
    const float* __restrict__ c_w2, const float* __restrict__ c_b2,
    const float* __restrict__ c_w3, const float* __restrict__ c_b3,
    const float* __restrict__ t_w1, const float* __restrict__ t_b1,
    const float* __restrict__ t_w2, const float* __restrict__ t_b2,
    const float* __restrict__ t_w3, const float* __restrict__ t_b3,
    const float* __restrict__ f_w1, const float* __restrict__ f_b1,
    const float* __restrict__ f_w2, const float* __restrict__ f_b2,
    const float* __restrict__ f_w3, const float* __restrict__ f_b3,
    float* __restrict__ out)
{
    // LDS arena: 8200 u32 = 32800 B -> 4 wg/CU.
    //  [0,7000)   xT   f32 x-chunk 250 rows x 28      (A-L1 staging)
    //             h1L  u32 bf16x2 250 x 17 [0,4250)   (after L1, dead after B)
    //             ho32 [0,2250) + uv32 [2250,6500)    (B..E1 / B..C, alias)
    //             h1t [2250,3900), h2t [3900,5550)    (E1..E3, alias uv32)
    //  [7000,8000) sPm f32 (C..D) / sT f32 25x33 (E3..F)
    //  [8000,8200) sG  f32 25x8 (D..E1)
    __shared__ unsigned smem_u[8200];
    float*    const xT   = (float*)smem_u;
    unsigned* const h1L  = smem_u;
    unsigned* const ho32 = smem_u;
    unsigned* const uv32 = smem_u + 2250;
    unsigned* const h1t  = smem_u + 2250;
    unsigned* const h2t  = smem_u + 3900;
    float*    const sPm  = (float*)(smem_u + 7000);
    float*    const sT   = (float*)(smem_u + 7000);
    float*    const sG   = (float*)(smem_u + 8000);

    const int tid = threadIdx.x;
    const int wg  = blockIdx.x;
    const int s0  = wg * SPB;
    const int vs  = (NB - s0 < SPB) ? (NB - s0) : SPB;
    const int vr  = vs * 10;
    const float* xg = x + (size_t)s0 * 1400;

    // ===== Phase A-L1: hero layer 1 (140->32), transpose layout =====
    // thread = (slot = row mod 32, sub = output quad). Weights via vector L1.
    const int slot = tid >> 3;        // 0..31
    const int sub  = tid & 7;         // 0..7
    const int o0   = sub << 2;

    float acc[8][4];
    {
        const float4 bb = *(const float4*)(h_b1 + o0);
        #pragma unroll
        for (int i = 0; i < 8; ++i) {
            acc[i][0] = bb.x; acc[i][1] = bb.y; acc[i][2] = bb.z; acc[i][3] = bb.w;
        }
    }
    for (int c = 0; c < 5; ++c) {     // 5 K-chunks of 28
        // coalesced stage: 250 rows x 7 float4
        for (int idx = tid; idx < vr * 7; idx += THREADS) {
            const int r = idx / 7, q = idx % 7;
            *(float4*)(xT + r * 28 + q * 4) =
                *(const float4*)(xg + r * 140 + c * 28 + q * 4);
        }
        __syncthreads();
        const float* wbase = h_w1 + c * 28 * 32 + o0;
        #pragma unroll 4
        for (int kk = 0; kk < 28; ++kk) {
            const float4 w = *(const float4*)(wbase + kk * 32);  // L1-hot
            #pragma unroll
            for (int i = 0; i < 8; ++i) {
                const float xk = xT[(slot + 32 * i) * 28 + kk];  // 8-way bcast, conflict-free
                acc[i][0] = fmaf(xk, w.x, acc[i][0]);
                acc[i][1] = fmaf(xk, w.y, acc[i][1]);
                acc[i][2] = fmaf(xk, w.z, acc[i][2]);
                acc[i][3] = fmaf(xk, w.w, acc[i][3]);
            }
        }
        __syncthreads();              // xT consumed before next stage
    }
    // write h1 (relu) to LDS bf16x2, row stride 17 (xT dead; barrier above)
    #pragma unroll
    for (int i = 0; i < 8; ++i) {
        const int r = slot + 32 * i;
        if (r < vr) {
            h1L[r * 17 + sub * 2]     = pack_bf(fmaxf(acc[i][0], 0.f), fmaxf(acc[i][1], 0.f));
            h1L[r * 17 + sub * 2 + 1] = pack_bf(fmaxf(acc[i][2], 0.f), fmaxf(acc[i][3], 0.f));
        }
    }
    __syncthreads();

    // ===== Phase B: row-per-lane L2/L3/u,v (SGPR weights, 8KB < K$) =====
    float h1[32];
    if (tid < vr) {
        #pragma unroll
        for (int cc = 0; cc < 16; ++cc) {
            const unsigned p = h1L[tid * 17 + cc];
            h1[2 * cc]     = bf_lo(p);
            h1[2 * cc + 1] = bf_hi(p);
        }
    }
    __syncthreads();                  // all h1L reads done before ho32/uv32 overwrite
    if (tid < vr) {
        // layer 2 (32->32) -- full unroll, static indexing
        float a2[32];
        #pragma unroll
        for (int o = 0; o < 32; ++o) a2[o] = h_b2[o];
        #pragma unroll
        for (int k = 0; k < 32; ++k) {
            const float hk = h1[k];
            const float* wr = h_w2 + k * 32;
            #pragma unroll
            for (int o = 0; o < 32; ++o) a2[o] = fmaf(hk, wr[o], a2[o]);
        }
        #pragma unroll
        for (int o = 0; o < 32; ++o) a2[o] = fmaxf(a2[o], 0.f);

        // layer 3 (32->16, linear)
        float ho[16];
        #pragma unroll
        for (int o = 0; o < 16; ++o) ho[o] = h_b3[o];
        #pragma unroll
        for (int k = 0; k < 32; ++k) {
            const float hk = a2[k];
            const float* wr = h_w3 + k * 16;
            #pragma unroll
            for (int o = 0; o < 16; ++o) ho[o] = fmaf(hk, wr[o], ho[o]);
        }

        // u = ho @ cW1[:16], v = ho @ cW1[16:]
        float u[16], v[16];
        #pragma unroll
        for (int o = 0; o < 16; ++o) { u[o] = 0.f; v[o] = 0.f; }
        #pragma unroll
        for (int k = 0; k < 16; ++k) {
            const float hk = ho[k];
            const float* wu = c_w1 + k * 16;
            const float* wv = c_w1 + (16 + k) * 16;
            #pragma unroll
            for (int o = 0; o < 16; ++o) {
                u[o] = fmaf(hk, wu[o], u[o]);
                v[o] = fmaf(hk, wv[o], v[o]);
            }
        }

        #pragma unroll
        for (int cc = 0; cc < 8; ++cc)
            ho32[tid * 9 + cc] = pack_bf(ho[2 * cc], ho[2 * cc + 1]);
        #pragma unroll
        for (int cc = 0; cc < 8; ++cc) {
            uv32[tid * 17 + cc]     = pack_bf(u[2 * cc], u[2 * cc + 1]);
            uv32[tid * 17 + 8 + cc] = pack_bf(v[2 * cc], v[2 * cc + 1]);
        }
    }
    __syncthreads();

    // ===== Phase C: 50 pairs/sample, counter L2/L3 + pool2, 10 lanes/sample =====
    if (tid < vs * 10) {
        const int s = tid / 10;
        const int t10 = tid % 10;
        const int half = t10 / 5;
        const int pg = t10 % 5;
        float pm0 = -1e30f, pm1 = -1e30f, pm2 = -1e30f, pm3 = -1e30f;
        for (int n = 0; n < 5; ++n) {
            int i, j;
            if (half == 0) { i = pg; j = 5 + n; } else { i = 5 + pg; j = n; }
            const unsigned* ur  = uv32 + (s * 10 + i) * 17;
            const unsigned* vrw = uv32 + (s * 10 + j) * 17 + 8;
            float h1p[16];
            #pragma unroll
            for (int cc = 0; cc < 8; ++cc) {
                const unsigned uu = ur[cc], vv = vrw[cc];
                h1p[2 * cc]     = fmaxf(bf_lo(uu) + bf_lo(vv) + c_b1[2 * cc], 0.f);
                h1p[2 * cc + 1] = fmaxf(bf_hi(uu) + bf_hi(vv) + c_b1[2 * cc + 1], 0.f);
            }
            float a[16];
            #pragma unroll
            for (int o = 0; o < 16; ++o) a[o] = c_b2[o];
            #pragma unroll
            for (int k = 0; k < 16; ++k) {
                const float hk = h1p[k];
                const float* wr = c_w2 + k * 16;
                #pragma unroll
                for (int o = 0; o < 16; ++o) a[o] = fmaf(hk, wr[o], a[o]);
            }
            float c3[8];
            #pragma unroll
            for (int o = 0; o < 8; ++o) c3[o] = c_b3[o];
            #pragma unroll
            for (int k = 0; k < 16; ++k) {
                const float hk = fmaxf(a[k], 0.f);
                const float* wr = c_w3 + k * 8;
                #pragma unroll
                for (int o = 0; o < 8; ++o) c3[o] = fmaf(hk, wr[o], c3[o]);
            }
            pm0 = fmaxf(pm0, fmaxf(c3[0], c3[1]));
            pm1 = fmaxf(pm1, fmaxf(c3[2], c3[3]));
            pm2 = fmaxf(pm2, fmaxf(c3[4], c3[5]));
            pm3 = fmaxf(pm3, fmaxf(c3[6], c3[7]));
        }
        float* dst = sPm + ((s * 2 + half) * 5 + pg) * 4;
        dst[0] = pm0; dst[1] = pm1; dst[2] = pm2; dst[3] = pm3;
    }
    __syncthreads();

    // ===== Phase D: max over 5 groups -> g =====
    if (tid < vs * 8) {
        const int s = tid >> 3;
        const int r = tid & 7;            // half*4 + m
        const int half = r >> 2, m = r & 3;
        float mx = -1e30f;
        #pragma unroll
        for (int pg = 0; pg < 5; ++pg)
            mx = fmaxf(mx, sPm[((s * 2 + half) * 5 + pg) * 4 + m]);
        sG[s * 8 + r] = mx;
    }
    __syncthreads();

    // ===== Phase E1: team layer 1 (84 -> 64), 4 lanes/row =====
    if (tid < vs * 8) {
        const int s = tid >> 3;
        const int half = (tid >> 2) & 1;
        const int q = tid & 3;
        const int oq = q * 16;
        float a[16];
        #pragma unroll
        for (int o = 0; o < 16; ++o) a[o] = t_b1[oq + o];
        for (int h5 = 0; h5 < 5; ++h5) {
            const int row = s * 10 + half * 5 + h5;
            #pragma unroll
            for (int cc = 0; cc < 8; ++cc) {
                const unsigned hv = ho32[row * 9 + cc];
                const float x0 = bf_lo(hv), x1 = bf_hi(hv);
                const int k0 = h5 * 16 + 2 * cc;
                #pragma unroll
                for (int ob = 0; ob < 4; ++ob) {
                    const float4 w0 = *(const float4*)(t_w1 + k0 * 64 + oq + ob * 4);
                    const float4 w1 = *(const float4*)(t_w1 + (k0 + 1) * 64 + oq + ob * 4);
                    a[ob * 4 + 0] = fmaf(x0, w0.x, a[ob * 4 + 0]);
                    a[ob * 4 + 1] = fmaf(x0, w0.y, a[ob * 4 + 1]);
                    a[ob * 4 + 2] = fmaf(x0, w0.z, a[ob * 4 + 2]);
                    a[ob * 4 + 3] = fmaf(x0, w0.w, a[ob * 4 + 3]);
                    a[ob * 4 + 0] = fmaf(x1, w1.x, a[ob * 4 + 0]);
                    a[ob * 4 + 1] = fmaf(x1, w1.y, a[ob * 4 + 1]);
                    a[ob * 4 + 2] = fmaf(x1, w1.z, a[ob * 4 + 2]);
                    a[ob * 4 + 3] = fmaf(x1, w1.w, a[ob * 4 + 3]);
                }
            }
        }
        #pragma unroll
        for (int m = 0; m < 4; ++m) {
            const float gv = sG[s * 8 + half * 4 + m];
            #pragma unroll
            for (int ob = 0; ob < 4; ++ob) {
                const float4 w = *(const float4*)(t_w1 + (80 + m) * 64 + oq + ob * 4);
                a[ob * 4 + 0] = fmaf(gv, w.x, a[ob * 4 + 0]);
                a[ob * 4 + 1] = fmaf(gv, w.y, a[ob * 4 + 1]);
                a[ob * 4 + 2] = fmaf(gv, w.z, a[ob * 4 + 2]);
                a[ob * 4 + 3] = fmaf(gv, w.w, a[ob * 4 + 3]);
            }
        }
        const int row48 = s * 2 + half;
        #pragma unroll
        for (int cc = 0; cc < 8; ++cc)
            h1t[row48 * 33 + q * 8 + cc] =
                pack_bf(fmaxf(a[2 * cc], 0.f), fmaxf(a[2 * cc + 1], 0.f));
    }
    __syncthreads();

    // ===== Phase E2: team layer 2 (64 -> 64) =====
    if (tid < vs * 8) {
        const int s = tid >> 3;
        const int half = (tid >> 2) & 1;
        const int q = tid & 3;
        const int oq = q * 16;
        const int row48 = s * 2 + half;
        float a[16];
        #pragma unroll
        for (int o = 0; o < 16; ++o) a[o] = t_b2[oq + o];
        #pragma unroll 8
        for (int cc = 0; cc < 32; ++cc) {
            const unsigned hv = h1t[row48 * 33 + cc];
            const float x0 = bf_lo(hv), x1 = bf_hi(hv);
            #pragma unroll
            for (int ob = 0; ob < 4; ++ob) {
                const float4 w0 = *(const float4*)(t_w2 + (2 * cc) * 64 + oq + ob * 4);
                const float4 w1 = *(const float4*)(t_w2 + (2 * cc + 1) * 64 + oq + ob * 4);
                a[ob * 4 + 0] = fmaf(x0, w0.x, a[ob * 4 + 0]);
                a[ob * 4 + 1] = fmaf(x0, w0.y, a[ob * 4 + 1]);
                a[ob * 4 + 2] = fmaf(x0, w0.z, a[ob * 4 + 2]);
                a[ob * 4 + 3] = fmaf(x0, w0.w, a[ob * 4 + 3]);
                a[ob * 4 + 0] = fmaf(x1, w1.x, a[ob * 4 + 0]);
                a[ob * 4 + 1] = fmaf(x1, w1.y, a[ob * 4 + 1]);
                a[ob * 4 + 2] = fmaf(x1, w1.z, a[ob * 4 + 2]);
                a[ob * 4 + 3] = fmaf(x1, w1.w, a[ob * 4 + 3]);
            }
        }
        #pragma unroll
        for (int cc = 0; cc < 8; ++cc)
            h2t[row48 * 33 + q * 8 + cc] =
                pack_bf(fmaxf(a[2 * cc], 0.f), fmaxf(a[2 * cc + 1], 0.f));
    }
    __syncthreads();

    // ===== Phase E3: team layer 3 (64 -> 16, linear) =====
    if (tid < vs * 8) {
        const int s = tid >> 3;
        const int half = (tid >> 2) & 1;
        const int q = tid & 3;
        const int oq = q * 4;
        const int row48 = s * 2 + half;
        float a0s = t_b3[oq], a1s = t_b3[oq + 1], a2s = t_b3[oq + 2], a3s = t_b3[oq + 3];
        #pragma unroll 8
        for (int cc = 0; cc < 32; ++cc) {
            const unsigned hv = h2t[row48 * 33 + cc];
            const float x0 = bf_lo(hv), x1 = bf_hi(hv);
            const float4 w0 = *(const float4*)(t_w3 + (2 * cc) * 16 + oq);
            const float4 w1 = *(const float4*)(t_w3 + (2 * cc + 1) * 16 + oq);
            a0s = fmaf(x0, w0.x, a0s); a1s = fmaf(x0, w0.y, a1s);
            a2s = fmaf(x0, w0.z, a2s); a3s = fmaf(x0, w0.w, a3s);
            a0s = fmaf(x1, w1.x, a0s); a1s = fmaf(x1, w1.y, a1s);
            a2s = fmaf(x1, w1.z, a2s); a3s = fmaf(x1, w1.w, a3s);
        }
        float* dst = sT + s * 33 + half * 16 + oq;
        dst[0] = a0s; dst[1] = a1s; dst[2] = a2s; dst[3] = a3s;
    }
    __syncthreads();

    // ===== Phase F: final MLP (32->16->16->2) + softmax, 1 lane/sample =====
    if (tid < vs) {
        const float* tr = sT + tid * 33;
        float g1[16];
        #pragma unroll
        for (int o = 0; o < 16; ++o) g1[o] = f_b1[o];
        #pragma unroll
        for (int k = 0; k < 32; ++k) {
            const float hk = tr[k];
            const float* wr = f_w1 + k * 16;
            #pragma unroll
            for (int o = 0; o < 16; ++o) g1[o] = fmaf(hk, wr[o], g1[o]);
        }
        float g2[16];
        #pragma unroll
        for (int o = 0; o < 16; ++o) g2[o] = f_b2[o];
        #pragma unroll
        for (int k = 0; k < 16; ++k) {
            const float hk = fmaxf(g1[k], 0.f);
            const float* wr = f_w2 + k * 16;
            #pragma unroll
            for (int o = 0; o < 16; ++o) g2[o] = fmaf(hk, wr[o], g2[o]);
        }
        float l0 = f_b3[0], l1 = f_b3[1];
        #pragma unroll
        for (int k = 0; k < 16; ++k) {
            const float hk = fmaxf(g2[k], 0.f);
            l0 = fmaf(hk, f_w3[2 * k], l0);
            l1 = fmaf(hk, f_w3[2 * k + 1], l1);
        }
        const float e = expf(l1 - l0);
        const float p0 = 1.f / (1.f + e);
        out[(size_t)(s0 + tid) * 2]     = p0;
        out[(size_t)(s0 + tid) * 2 + 1] = 1.f - p0;
    }
}

extern "C" void kernel_launch(void* const* d_in, const int* in_sizes, int n_in,
                              void* d_out, int out_size, void* d_ws, size_t ws_size,
                              hipStream_t stream) {
    (void)in_sizes; (void)n_in; (void)d_ws; (void)ws_size; (void)out_size;
    const float* x    = (const float*)d_in[0];
    const float* h_w1 = (const float*)d_in[1];  const float* h_b1 = (const float*)d_in[2];
    const float* h_w2 = (const float*)d_in[3];  const float* h_b2 = (const float*)d_in[4];
    const float* h_w3 = (const float*)d_in[5];  const float* h_b3 = (const float*)d_in[6];
    const float* c_w1 = (const float*)d_in[7];  const float* c_b1 = (const float*)d_in[8];
    const float* c_w2 = (const float*)d_in[9];  const float* c_b2 = (const float*)d_in[10];
    const float* c_w3 = (const float*)d_in[11]; const float* c_b3 = (const float*)d_in[12];
    const float* t_w1 = (const float*)d_in[13]; const float* t_b1 = (const float*)d_in[14];
    const float* t_w2 = (const float*)d_in[15]; const float* t_b2 = (const float*)d_in[16];
    const float* t_w3 = (const float*)d_in[17]; const float* t_b3 = (const float*)d_in[18];
    const float* f_w1 = (const float*)d_in[19]; const float* f_b1 = (const float*)d_in[20];
    const float* f_w2 = (const float*)d_in[21]; const float* f_b2 = (const float*)d_in[22];
    const float* f_w3 = (const float*)d_in[23]; const float* f_b3 = (const float*)d_in[24];
    float* out = (float*)d_out;

    const int grid = (NB + SPB - 1) / SPB;   // 2622 workgroups
    fused_model_kernel<<<grid, THREADS, 0, stream>>>(
        x, h_w1, h_b1, h_w2, h_b2, h_w3, h_b3,
        c_w1, c_b1, c_w2, c_b2, c_w3, c_b3,
        t_w1, t_b1, t_w2, t_b2, t_w3, t_b3,
        f_w1, f_b1, f_w2, f_b2, f_w3, f_b3,
        out);
}

// Round 11
// 535.923 us; speedup vs baseline: 1.0113x; 1.0113x over previous
//
#include <hip/hip_runtime.h>
#include <hip/hip_bf16.h>
#include <math.h>

// Round 11: compact code. r7-r10 plateau at VALUBusy 35-40% across four
// different phase-A load arrangements => shared suspect is the ~35-50KB of
// fully-unrolled straight-line code thrashing the 32KB I$ + destroying the
// s_load pipelining window. Rewrite: ALL k-loops rolled (activations routed
// through LDS, which is runtime-addressable; register arrays only ever
// indexed by the unrolled inner o-loop). Hero chain h1/h2/uv share ONE LDS
// region: each lane touches only its own stride-17 row (odd stride =>
// conflict-free, no barriers needed between hero layers).
//  - x: rolled 34-iter loop, 1-deep manual prefetch (scalar float4 vars).
//  - weights: wave-uniform s_load chunks inside small loops (pipelinable).
//  - code ~12KB (was ~40KB) -> I$ resident.

#define THREADS 256
#define SPB 25
#define NB 65536

__device__ __forceinline__ unsigned bfr(float f) {
    unsigned u = __float_as_uint(f);
    return (u + 0x7fffu + ((u >> 16) & 1u)) >> 16;   // RNE to bf16
}
__device__ __forceinline__ unsigned pack_bf(float a, float b) {
    return bfr(a) | (bfr(b) << 16);
}
__device__ __forceinline__ float bf_lo(unsigned u) { return __uint_as_float(u << 16); }
__device__ __forceinline__ float bf_hi(unsigned u) { return __uint_as_float(u & 0xffff0000u); }

__global__ __launch_bounds__(THREADS, 4) void fused_model_kernel(
    const float* __restrict__ x,
    const float* __restrict__ h_w1, const float* __restrict__ h_b1,
    const float* __restrict__ h_w2, const float* __restrict__ h_b2,
    const float* __restrict__ h_w3, const float* __restrict__ h_b3,
    const float* __restrict__ c_w1, const float* __restrict__ c_b1,
    const float* __restrict__ c_w2, const float* __restrict__ c_b2,
    const float* __restrict__ c_w3, const float* __restrict__ c_b3,
    const float* __restrict__ t_w1, const float* __restrict__ t_b1,
    const float* __restrict__ t_w2, const float* __restrict__ t_b2,
    const float* __restrict__ t_w3, const float* __restrict__ t_b3,
    const float* __restrict__ f_w1, const float* __restrict__ f_b1,
    const float* __restrict__ f_w2, const float* __restrict__ f_b2,
    const float* __restrict__ f_w3, const float* __restrict__ f_b3,
    float* __restrict__ out)
{
    // LDS arena: 7700 u32 = 30800 B.
    //  [0,4250)    X: hero-chain rows, 250 x stride 17 (h1/h2/uv alias --
    //              each lane touches only its own row, writes follow reads)
    //              later: h1t [0,1650) 50x33 (E1..E2), h2t [1650,3300) (E2..E3)
    //              later: sF1 [3300,3725) f32 25x17 (F scratch)
    //  [4250,6500) ho32 u32 bf16x2 250 x 9 (end-L3 .. E1)
    //  [6500,7500) sPm f32 (C..D) / sT f32 25x33 (E3..F)
    //  [7500,7700) sG f32 25x8 (D..E1)
    __shared__ unsigned smem_u[7700];
    unsigned* const hX   = smem_u;            // hero rows / uv32
    unsigned* const h1t  = smem_u;
    unsigned* const h2t  = smem_u + 1650;
    float*    const sF1  = (float*)(smem_u + 3300);
    unsigned* const ho32 = smem_u + 4250;
    float*    const sPm  = (float*)(smem_u + 6500);
    float*    const sT   = (float*)(smem_u + 6500);
    float*    const sG   = (float*)(smem_u + 7500);

    const int tid = threadIdx.x;
    const int wg  = blockIdx.x;
    const int s0  = wg * SPB;
    const int vs  = (NB - s0 < SPB) ? (NB - s0) : SPB;
    const int vr  = vs * 10;

    // ===== Phase A/B: hero chain, row-per-lane, rolled k-loops =====
    if (tid < vr) {
        const float* xr = x + ((size_t)s0 * 10 + tid) * 140;

        // ---- L1: 140 -> 32, rolled over 35 q-steps, 1-deep x prefetch ----
        float acc[32];
        #pragma unroll
        for (int o = 0; o < 32; ++o) acc[o] = h_b1[o];
        float4 xv = *(const float4*)xr;
        for (int q = 0; q < 34; ++q) {
            const float4 nxt = *(const float4*)(xr + (q + 1) * 4);
            const float* wr = h_w1 + q * 128;            // uniform -> s_load
            #pragma unroll
            for (int o = 0; o < 32; ++o) acc[o] = fmaf(xv.x, wr[o], acc[o]);
            #pragma unroll
            for (int o = 0; o < 32; ++o) acc[o] = fmaf(xv.y, wr[32 + o], acc[o]);
            #pragma unroll
            for (int o = 0; o < 32; ++o) acc[o] = fmaf(xv.z, wr[64 + o], acc[o]);
            #pragma unroll
            for (int o = 0; o < 32; ++o) acc[o] = fmaf(xv.w, wr[96 + o], acc[o]);
            xv = nxt;
        }
        {   // peeled last q (34)
            const float* wr = h_w1 + 34 * 128;
            #pragma unroll
            for (int o = 0; o < 32; ++o) acc[o] = fmaf(xv.x, wr[o], acc[o]);
            #pragma unroll
            for (int o = 0; o < 32; ++o) acc[o] = fmaf(xv.y, wr[32 + o], acc[o]);
            #pragma unroll
            for (int o = 0; o < 32; ++o) acc[o] = fmaf(xv.z, wr[64 + o], acc[o]);
            #pragma unroll
            for (int o = 0; o < 32; ++o) acc[o] = fmaf(xv.w, wr[96 + o], acc[o]);
        }
        // relu + pack h1 -> own LDS row
        #pragma unroll
        for (int cc = 0; cc < 16; ++cc)
            hX[tid * 17 + cc] = pack_bf(fmaxf(acc[2 * cc], 0.f),
                                        fmaxf(acc[2 * cc + 1], 0.f));

        // ---- L2: 32 -> 32, rolled (reads own row, then overwrites it) ----
        float a2[32];
        #pragma unroll
        for (int o = 0; o < 32; ++o) a2[o] = h_b2[o];
        for (int kk = 0; kk < 16; ++kk) {
            const unsigned p = hX[tid * 17 + kk];
            const float hk0 = bf_lo(p), hk1 = bf_hi(p);
            const float* w0 = h_w2 + (2 * kk) * 32;
            const float* w1 = h_w2 + (2 * kk + 1) * 32;
            #pragma unroll
            for (int o = 0; o < 32; ++o) a2[o] = fmaf(hk0, w0[o], a2[o]);
            #pragma unroll
            for (int o = 0; o < 32; ++o) a2[o] = fmaf(hk1, w1[o], a2[o]);
        }
        #pragma unroll
        for (int cc = 0; cc < 16; ++cc)
            hX[tid * 17 + cc] = pack_bf(fmaxf(a2[2 * cc], 0.f),
                                        fmaxf(a2[2 * cc + 1], 0.f));

        // ---- L3: 32 -> 16 (linear), rolled ----
        float ho[16];
        #pragma unroll
        for (int o = 0; o < 16; ++o) ho[o] = h_b3[o];
        for (int kk = 0; kk < 16; ++kk) {
            const unsigned p = hX[tid * 17 + kk];
            const float hk0 = bf_lo(p), hk1 = bf_hi(p);
            const float* w0 = h_w3 + (2 * kk) * 16;
            const float* w1 = h_w3 + (2 * kk + 1) * 16;
            #pragma unroll
            for (int o = 0; o < 16; ++o) ho[o] = fmaf(hk0, w0[o], ho[o]);
            #pragma unroll
            for (int o = 0; o < 16; ++o) ho[o] = fmaf(hk1, w1[o], ho[o]);
        }
        #pragma unroll
        for (int cc = 0; cc < 8; ++cc)
            ho32[tid * 9 + cc] = pack_bf(ho[2 * cc], ho[2 * cc + 1]);

        // ---- u/v: 16 -> 16+16, rolled over ho32 (just written, own row) ----
        float u[16], v[16];
        #pragma unroll
        for (int o = 0; o < 16; ++o) { u[o] = 0.f; v[o] = 0.f; }
        for (int kk = 0; kk < 8; ++kk) {
            const unsigned p = ho32[tid * 9 + kk];
            const float hk0 = bf_lo(p), hk1 = bf_hi(p);
            const float* wu0 = c_w1 + (2 * kk) * 16;
            const float* wu1 = c_w1 + (2 * kk + 1) * 16;
            const float* wv0 = c_w1 + (16 + 2 * kk) * 16;
            const float* wv1 = c_w1 + (16 + 2 * kk + 1) * 16;
            #pragma unroll
            for (int o = 0; o < 16; ++o) {
                u[o] = fmaf(hk0, wu0[o], u[o]);
                u[o] = fmaf(hk1, wu1[o], u[o]);
                v[o] = fmaf(hk0, wv0[o], v[o]);
                v[o] = fmaf(hk1, wv1[o], v[o]);
            }
        }
        // pack u|v into own X row (h1/h2 slots dead for this lane)
        #pragma unroll
        for (int cc = 0; cc < 8; ++cc) {
            hX[tid * 17 + cc]     = pack_bf(u[2 * cc], u[2 * cc + 1]);
            hX[tid * 17 + 8 + cc] = pack_bf(v[2 * cc], v[2 * cc + 1]);
        }
    }
    __syncthreads();

    // ===== Phase C: 50 pairs/sample, counter L2/L3 + pool2, 10 lanes/sample =====
    if (tid < vs * 10) {
        const int s = tid / 10;
        const int t10 = tid % 10;
        const int half = t10 / 5;
        const int pg = t10 % 5;
        float pm0 = -1e30f, pm1 = -1e30f, pm2 = -1e30f, pm3 = -1e30f;
        for (int n = 0; n < 5; ++n) {
            int i, j;
            if (half == 0) { i = pg; j = 5 + n; } else { i = 5 + pg; j = n; }
            const unsigned* ur  = hX + (s * 10 + i) * 17;
            const unsigned* vrw = hX + (s * 10 + j) * 17 + 8;
            float h1p[16];
            #pragma unroll
            for (int cc = 0; cc < 8; ++cc) {
                const unsigned uu = ur[cc], vv = vrw[cc];
                h1p[2 * cc]     = fmaxf(bf_lo(uu) + bf_lo(vv) + c_b1[2 * cc], 0.f);
                h1p[2 * cc + 1] = fmaxf(bf_hi(uu) + bf_hi(vv) + c_b1[2 * cc + 1], 0.f);
            }
            float a[16];
            #pragma unroll
            for (int o = 0; o < 16; ++o) a[o] = c_b2[o];
            #pragma unroll
            for (int k = 0; k < 16; ++k) {
                const float hk = h1p[k];
                const float* wr = c_w2 + k * 16;
                #pragma unroll
                for (int o = 0; o < 16; ++o) a[o] = fmaf(hk, wr[o], a[o]);
            }
            float c3[8];
            #pragma unroll
            for (int o = 0; o < 8; ++o) c3[o] = c_b3[o];
            #pragma unroll
            for (int k = 0; k < 16; ++k) {
                const float hk = fmaxf(a[k], 0.f);
                const float* wr = c_w3 + k * 8;
                #pragma unroll
                for (int o = 0; o < 8; ++o) c3[o] = fmaf(hk, wr[o], c3[o]);
            }
            pm0 = fmaxf(pm0, fmaxf(c3[0], c3[1]));
            pm1 = fmaxf(pm1, fmaxf(c3[2], c3[3]));
            pm2 = fmaxf(pm2, fmaxf(c3[4], c3[5]));
            pm3 = fmaxf(pm3, fmaxf(c3[6], c3[7]));
        }
        float* dst = sPm + ((s * 2 + half) * 5 + pg) * 4;
        dst[0] = pm0; dst[1] = pm1; dst[2] = pm2; dst[3] = pm3;
    }
    __syncthreads();

    // ===== Phase D: max over 5 groups -> g =====
    if (tid < vs * 8) {
        const int s = tid >> 3;
        const int r = tid & 7;
        const int half = r >> 2, m = r & 3;
        float mx = -1e30f;
        #pragma unroll
        for (int pg = 0; pg < 5; ++pg)
            mx = fmaxf(mx, sPm[((s * 2 + half) * 5 + pg) * 4 + m]);
        sG[s * 8 + r] = mx;
    }
    __syncthreads();

    // ===== Phase E1: team layer 1 (84 -> 64), 4 lanes/row =====
    if (tid < vs * 8) {
        const int s = tid >> 3;
        const int half = (tid >> 2) & 1;
        const int q = tid & 3;
        const int oq = q * 16;
        float a[16];
        #pragma unroll
        for (int o = 0; o < 16; ++o) a[o] = t_b1[oq + o];
        for (int h5 = 0; h5 < 5; ++h5) {
            const int row = s * 10 + half * 5 + h5;
            #pragma unroll
            for (int cc = 0; cc < 8; ++cc) {
                const unsigned hv = ho32[row * 9 + cc];
                const float x0 = bf_lo(hv), x1 = bf_hi(hv);
                const int k0 = h5 * 16 + 2 * cc;
                #pragma unroll
                for (int ob = 0; ob < 4; ++ob) {
                    const float4 w0 = *(const float4*)(t_w1 + k0 * 64 + oq + ob * 4);
                    const float4 w1 = *(const float4*)(t_w1 + (k0 + 1) * 64 + oq + ob * 4);
                    a[ob * 4 + 0] = fmaf(x0, w0.x, a[ob * 4 + 0]);
                    a[ob * 4 + 1] = fmaf(x0, w0.y, a[ob * 4 + 1]);
                    a[ob * 4 + 2] = fmaf(x0, w0.z, a[ob * 4 + 2]);
                    a[ob * 4 + 3] = fmaf(x0, w0.w, a[ob * 4 + 3]);
                    a[ob * 4 + 0] = fmaf(x1, w1.x, a[ob * 4 + 0]);
                    a[ob * 4 + 1] = fmaf(x1, w1.y, a[ob * 4 + 1]);
                    a[ob * 4 + 2] = fmaf(x1, w1.z, a[ob * 4 + 2]);
                    a[ob * 4 + 3] = fmaf(x1, w1.w, a[ob * 4 + 3]);
                }
            }
        }
        #pragma unroll
        for (int m = 0; m < 4; ++m) {
            const float gv = sG[s * 8 + half * 4 + m];
            #pragma unroll
            for (int ob = 0; ob < 4; ++ob) {
                const float4 w = *(const float4*)(t_w1 + (80 + m) * 64 + oq + ob * 4);
                a[ob * 4 + 0] = fmaf(gv, w.x, a[ob * 4 + 0]);
                a[ob * 4 + 1] = fmaf(gv, w.y, a[ob * 4 + 1]);
                a[ob * 4 + 2] = fmaf(gv, w.z, a[ob * 4 + 2]);
                a[ob * 4 + 3] = fmaf(gv, w.w, a[ob * 4 + 3]);
            }
        }
        const int row48 = s * 2 + half;
        #pragma unroll
        for (int cc = 0; cc < 8; ++cc)
            h1t[row48 * 33 + q * 8 + cc] =
                pack_bf(fmaxf(a[2 * cc], 0.f), fmaxf(a[2 * cc + 1], 0.f));
    }
    __syncthreads();

    // ===== Phase E2: team layer 2 (64 -> 64) =====
    if (tid < vs * 8) {
        const int s = tid >> 3;
        const int half = (tid >> 2) & 1;
        const int q = tid & 3;
        const int oq = q * 16;
        const int row48 = s * 2 + half;
        float a[16];
        #pragma unroll
        for (int o = 0; o < 16; ++o) a[o] = t_b2[oq + o];
        for (int cc = 0; cc < 32; ++cc) {       // rolled: h1t is LDS
            const unsigned hv = h1t[row48 * 33 + cc];
            const float x0 = bf_lo(hv), x1 = bf_hi(hv);
            #pragma unroll
            for (int ob = 0; ob < 4; ++ob) {
                const float4 w0 = *(const float4*)(t_w2 + (2 * cc) * 64 + oq + ob * 4);
                const float4 w1 = *(const float4*)(t_w2 + (2 * cc + 1) * 64 + oq + ob * 4);
                a[ob * 4 + 0] = fmaf(x0, w0.x, a[ob * 4 + 0]);
                a[ob * 4 + 1] = fmaf(x0, w0.y, a[ob * 4 + 1]);
                a[ob * 4 + 2] = fmaf(x0, w0.z, a[ob * 4 + 2]);
                a[ob * 4 + 3] = fmaf(x0, w0.w, a[ob * 4 + 3]);
                a[ob * 4 + 0] = fmaf(x1, w1.x, a[ob * 4 + 0]);
                a[ob * 4 + 1] = fmaf(x1, w1.y, a[ob * 4 + 1]);
                a[ob * 4 + 2] = fmaf(x1, w1.z, a[ob * 4 + 2]);
                a[ob * 4 + 3] = fmaf(x1, w1.w, a[ob * 4 + 3]);
            }
        }
        #pragma unroll
        for (int cc = 0; cc < 8; ++cc)
            h2t[row48 * 33 + q * 8 + cc] =
                pack_bf(fmaxf(a[2 * cc], 0.f), fmaxf(a[2 * cc + 1], 0.f));
    }
    __syncthreads();

    // ===== Phase E3: team layer 3 (64 -> 16, linear) =====
    if (tid < vs * 8) {
        const int s = tid >> 3;
        const int half = (tid >> 2) & 1;
        const int q = tid & 3;
        const int oq = q * 4;
        const int row48 = s * 2 + half;
        float a0s = t_b3[oq], a1s = t_b3[oq + 1], a2s = t_b3[oq + 2], a3s = t_b3[oq + 3];
        for (int cc = 0; cc < 32; ++cc) {       // rolled: h2t is LDS
            const unsigned hv = h2t[row48 * 33 + cc];
            const float x0 = bf_lo(hv), x1 = bf_hi(hv);
            const float4 w0 = *(const float4*)(t_w3 + (2 * cc) * 16 + oq);
            const float4 w1 = *(const float4*)(t_w3 + (2 * cc + 1) * 16 + oq);
            a0s = fmaf(x0, w0.x, a0s); a1s = fmaf(x0, w0.y, a1s);
            a2s = fmaf(x0, w0.z, a2s); a3s = fmaf(x0, w0.w, a3s);
            a0s = fmaf(x1, w1.x, a0s); a1s = fmaf(x1, w1.y, a1s);
            a2s = fmaf(x1, w1.z, a2s); a3s = fmaf(x1, w1.w, a3s);
        }
        float* dst = sT + s * 33 + half * 16 + oq;
        dst[0] = a0s; dst[1] = a1s; dst[2] = a2s; dst[3] = a3s;
    }
    __syncthreads();

    // ===== Phase F: final MLP (32->16->16->2) + softmax, 1 lane/sample, rolled =====
    if (tid < vs) {
        const float* tr = sT + tid * 33;
        float g1[16];
        #pragma unroll
        for (int o = 0; o < 16; ++o) g1[o] = f_b1[o];
        for (int k = 0; k < 32; ++k) {          // rolled: tr is LDS
            const float hk = tr[k];
            const float* wr = f_w1 + k * 16;
            #pragma unroll
            for (int o = 0; o < 16; ++o) g1[o] = fmaf(hk, wr[o], g1[o]);
        }
        #pragma unroll
        for (int o = 0; o < 16; ++o) sF1[tid * 17 + o] = fmaxf(g1[o], 0.f);

        float g2[16];
        #pragma unroll
        for (int o = 0; o < 16; ++o) g2[o] = f_b2[o];
        for (int k = 0; k < 16; ++k) {          // rolled: sF1 is LDS (own row)
            const float hk = sF1[tid * 17 + k];
            const float* wr = f_w2 + k * 16;
            #pragma unroll
            for (int o = 0; o < 16; ++o) g2[o] = fmaf(hk, wr[o], g2[o]);
        }
        #pragma unroll
        for (int o = 0; o < 16; ++o) sF1[tid * 17 + o] = fmaxf(g2[o], 0.f);

        float l0 = f_b3[0], l1 = f_b3[1];
        for (int k = 0; k < 16; ++k) {          // rolled
            const float hk = sF1[tid * 17 + k];
            l0 = fmaf(hk, f_w3[2 * k], l0);
            l1 = fmaf(hk, f_w3[2 * k + 1], l1);
        }
        const float e = expf(l1 - l0);
        const float p0 = 1.f / (1.f + e);
        out[(size_t)(s0 + tid) * 2]     = p0;
        out[(size_t)(s0 + tid) * 2 + 1] = 1.f - p0;
    }
}

extern "C" void kernel_launch(void* const* d_in, const int* in_sizes, int n_in,
                              void* d_out, int out_size, void* d_ws, size_t ws_size,
                              hipStream_t stream) {
    (void)in_sizes; (void)n_in; (void)d_ws; (void)ws_size; (void)out_size;
    const float* x    = (const float*)d_in[0];
    const float* h_w1 = (const float*)d_in[1];  const float* h_b1 = (const float*)d_in[2];
    const float* h_w2 = (const float*)d_in[3];  const float* h_b2 = (const float*)d_in[4];
    const float* h_w3 = (const float*)d_in[5];  const float* h_b3 = (const float*)d_in[6];
    const float* c_w1 = (const float*)d_in[7];  const float* c_b1 = (const float*)d_in[8];
    const float* c_w2 = (const float*)d_in[9];  const float* c_b2 = (const float*)d_in[10];
    const float* c_w3 = (const float*)d_in[11]; const float* c_b3 = (const float*)d_in[12];
    const float* t_w1 = (const float*)d_in[13]; const float* t_b1 = (const float*)d_in[14];
    const float* t_w2 = (const float*)d_in[15]; const float* t_b2 = (const float*)d_in[16];
    const float* t_w3 = (const float*)d_in[17]; const float* t_b3 = (const float*)d_in[18];
    const float* f_w1 = (const float*)d_in[19]; const float* f_b1 = (const float*)d_in[20];
    const float* f_w2 = (const float*)d_in[21]; const float* f_b2 = (const float*)d_in[22];
    const float* f_w3 = (const float*)d_in[23]; const float* f_b3 = (const float*)d_in[24];
    float* out = (float*)d_out;

    const int grid = (NB + SPB - 1) / SPB;   // 2622 workgroups
    fused_model_kernel<<<grid, THREADS, 0, stream>>>(
        x, h_w1, h_b1, h_w2, h_b2, h_w3, h_b3,
        c_w1, c_b1, c_w2, c_b2, c_w3, c_b3,
        t_w1, t_b1, t_w2, t_b2, t_w3, t_b3,
        f_w1, f_b1, f_w2, f_b2, f_w3, f_b3,
        out);
}

// Round 12
// 460.764 us; speedup vs baseline: 1.1762x; 1.1631x over previous
//
#include <hip/hip_runtime.h>
#include <hip/hip_bf16.h>
#include <math.h>

// Round 12: MFMA for hero L1 (70% of FLOPs).
//  r7-r11: five VALU-side variants all plateau (wave duty ~9%, VALUBusy
//  31-40%) -> the serialized weight-stream -> FMA chain is structural.
//  Rewrite L1 as mfma_f32_16x16x32_bf16: per wg [240x140]@[140x32],
//  15 row-tiles x 2 N-tiles x 5 K-chunks. Weights = 10 B-frags (40 VGPR)
//  loaded ONCE per wave. x staged per-chunk to LDS bf16 (stride-40 rows,
//  16B-aligned b128 A-frag reads). h1 written via verified C/D layout,
//  then r7's SGPR chain (L2/L3/uv; 8KB scalar weights = K$-resident) and
//  r7 phases C-F verbatim.

#define THREADS 256
#define SPB 24
#define NB 65536

typedef __attribute__((ext_vector_type(8))) short short8;   // 8 bf16 (4 VGPR)
typedef __attribute__((ext_vector_type(4))) float f32x4;    // 4 f32 acc

__device__ __forceinline__ unsigned bfr(float f) {
    unsigned u = __float_as_uint(f);
    return (u + 0x7fffu + ((u >> 16) & 1u)) >> 16;   // RNE to bf16
}
__device__ __forceinline__ unsigned pack_bf(float a, float b) {
    return bfr(a) | (bfr(b) << 16);
}
__device__ __forceinline__ float bf_lo(unsigned u) { return __uint_as_float(u << 16); }
__device__ __forceinline__ float bf_hi(unsigned u) { return __uint_as_float(u & 0xffff0000u); }

__global__ __launch_bounds__(THREADS, 4) void fused_model_kernel(
    const float* __restrict__ x,
    const float* __restrict__ h_w1, const float* __restrict__ h_b1,
    const float* __restrict__ h_w2, const float* __restrict__ h_b2,
    const float* __restrict__ h_w3, const float* __restrict__ h_b3,
    const float* __restrict__ c_w1, const float* __restrict__ c_b1,
    const float* __restrict__ c_w2, const float* __restrict__ c_b2,
    const float* __restrict__ c_w3, const float* __restrict__ c_b3,
    const float* __restrict__ t_w1, const float* __restrict__ t_b1,
    const float* __restrict__ t_w2, const float* __restrict__ t_b2,
    const float* __restrict__ t_w3, const float* __restrict__ t_b3,
    const float* __restrict__ f_w1, const float* __restrict__ f_b1,
    const float* __restrict__ f_w2, const float* __restrict__ f_b2,
    const float* __restrict__ f_w3, const float* __restrict__ f_b3,
    float* __restrict__ out)
{
    // LDS arena: 8112 u32 = 32448 B -> 4 wg/CU.
    //  [0,4800)    xchunk bf16 [240][40] (mfma staging)
    //              then h1/uv rows [240][17 u32] (stride-17, conflict-free)
    //              then h1t [0,1650) + h2t [1650,3300) (E phases)
    //  [4800,6960) ho32 u32 bf16x2 [240][9]
    //  [6960,7920) sPm f32 24*2*5*4 (C..D) / sT f32 24x33 (E3..F)
    //  [7920,8112) sG f32 24x8
    __shared__ unsigned smem_u[8112];
    unsigned* const hX   = smem_u;            // h1 / uv rows
    unsigned* const h1t  = smem_u;
    unsigned* const h2t  = smem_u + 1650;
    unsigned* const ho32 = smem_u + 4800;
    float*    const sPm  = (float*)(smem_u + 6960);
    float*    const sT   = (float*)(smem_u + 6960);
    float*    const sG   = (float*)(smem_u + 7920);

    const int tid = threadIdx.x;
    const int wg  = blockIdx.x;
    const int s0  = wg * SPB;
    const int vs  = (NB - s0 < SPB) ? (NB - s0) : SPB;
    const int vr  = vs * 10;

    const int lane = tid & 63;
    const int wv   = tid >> 6;        // wave 0..3
    const int lm   = lane & 15;       // m (A) / n (B) / col (D)
    const int lg   = lane >> 4;       // k-group / row-group

    // ===== Phase A-L1: MFMA [240x140]@[140x32] =====
    // B-fragments: w1 column-gather, once per wave. wf[c][nt][i] = bf16 of
    // w1[k=c*32+lg*8+i][nt*16+lm] (zero-pad k>=140).
    short8 wf[5][2];
    #pragma unroll
    for (int c = 0; c < 5; ++c)
        #pragma unroll
        for (int nt = 0; nt < 2; ++nt)
            #pragma unroll
            for (int i = 0; i < 8; ++i) {
                const int k = c * 32 + lg * 8 + i;
                const float w = (k < 140) ? h_w1[k * 32 + nt * 16 + lm] : 0.f;
                wf[c][nt][i] = (short)bfr(w);
            }

    f32x4 acc[4][2];
    #pragma unroll
    for (int t = 0; t < 4; ++t)
        #pragma unroll
        for (int nt = 0; nt < 2; ++nt) {
            const float b = h_b1[nt * 16 + lm];
            acc[t][nt] = (f32x4){b, b, b, b};
        }

    #pragma unroll
    for (int c = 0; c < 5; ++c) {     // static c: wf[c] stays register-resident
        // stage chunk c: x[.,c*32 .. c*32+31] -> bf16 LDS [240][40]
        for (int j = tid; j < vr * 8; j += THREADS) {
            const int row = j >> 3, q = j & 7;
            unsigned lo = 0, hi = 0;
            if (c < 4 || q < 3) {
                const float4 v = *(const float4*)(
                    x + ((size_t)s0 * 10 + row) * 140 + c * 32 + q * 4);
                lo = pack_bf(v.x, v.y);
                hi = pack_bf(v.z, v.w);
            }
            unsigned* dst = smem_u + row * 20 + q * 2;
            dst[0] = lo; dst[1] = hi;
        }
        __syncthreads();
        #pragma unroll
        for (int t = 0; t < 4; ++t) {
            const int tl = wv + 4 * t;             // tile 0..14
            if (tl < 15) {
                const int row = tl * 16 + lm;
                const short8 af = *(const short8*)(
                    (const unsigned short*)smem_u + row * 40 + lg * 8);
                acc[t][0] = __builtin_amdgcn_mfma_f32_16x16x32_bf16(af, wf[c][0], acc[t][0], 0, 0, 0);
                acc[t][1] = __builtin_amdgcn_mfma_f32_16x16x32_bf16(af, wf[c][1], acc[t][1], 0, 0, 0);
            }
        }
        __syncthreads();
    }

    // h1 writeback: D layout col=lane&15, row=lg*4+reg  [verified mapping]
    #pragma unroll
    for (int t = 0; t < 4; ++t) {
        const int tl = wv + 4 * t;
        if (tl < 15) {
            #pragma unroll
            for (int nt = 0; nt < 2; ++nt)
                #pragma unroll
                for (int r = 0; r < 4; ++r) {
                    const int row = tl * 16 + lg * 4 + r;
                    ((unsigned short*)smem_u)[row * 34 + nt * 16 + lm] =
                        (unsigned short)bfr(fmaxf(acc[t][nt][r], 0.f));
                }
        }
    }
    __syncthreads();

    // ===== Phase B: row-per-lane L2/L3/u,v (SGPR weights, 8KB K$-resident) =====
    if (tid < vr) {
        float h1v[32];
        #pragma unroll
        for (int i = 0; i < 16; ++i) {
            const unsigned p = hX[tid * 17 + i];
            h1v[2 * i]     = bf_lo(p);
            h1v[2 * i + 1] = bf_hi(p);
        }
        // L2 (32->32), full unroll
        float a2[32];
        #pragma unroll
        for (int o = 0; o < 32; ++o) a2[o] = h_b2[o];
        #pragma unroll
        for (int k = 0; k < 32; ++k) {
            const float hk = h1v[k];
            const float* wr = h_w2 + k * 32;
            #pragma unroll
            for (int o = 0; o < 32; ++o) a2[o] = fmaf(hk, wr[o], a2[o]);
        }
        #pragma unroll
        for (int o = 0; o < 32; ++o) a2[o] = fmaxf(a2[o], 0.f);

        // L3 (32->16, linear)
        float ho[16];
        #pragma unroll
        for (int o = 0; o < 16; ++o) ho[o] = h_b3[o];
        #pragma unroll
        for (int k = 0; k < 32; ++k) {
            const float hk = a2[k];
            const float* wr = h_w3 + k * 16;
            #pragma unroll
            for (int o = 0; o < 16; ++o) ho[o] = fmaf(hk, wr[o], ho[o]);
        }

        // u/v
        float u[16], v[16];
        #pragma unroll
        for (int o = 0; o < 16; ++o) { u[o] = 0.f; v[o] = 0.f; }
        #pragma unroll
        for (int k = 0; k < 16; ++k) {
            const float hk = ho[k];
            const float* wu = c_w1 + k * 16;
            const float* wvp = c_w1 + (16 + k) * 16;
            #pragma unroll
            for (int o = 0; o < 16; ++o) {
                u[o] = fmaf(hk, wu[o], u[o]);
                v[o] = fmaf(hk, wvp[o], v[o]);
            }
        }

        #pragma unroll
        for (int cc = 0; cc < 8; ++cc)
            ho32[tid * 9 + cc] = pack_bf(ho[2 * cc], ho[2 * cc + 1]);
        #pragma unroll
        for (int cc = 0; cc < 8; ++cc) {         // overwrite own h1 row with u|v
            hX[tid * 17 + cc]     = pack_bf(u[2 * cc], u[2 * cc + 1]);
            hX[tid * 17 + 8 + cc] = pack_bf(v[2 * cc], v[2 * cc + 1]);
        }
    }
    __syncthreads();

    // ===== Phase C: 50 pairs/sample, counter L2/L3 + pool2 =====
    if (tid < vs * 10) {
        const int s = tid / 10;
        const int t10 = tid % 10;
        const int half = t10 / 5;
        const int pg = t10 % 5;
        float pm0 = -1e30f, pm1 = -1e30f, pm2 = -1e30f, pm3 = -1e30f;
        for (int n = 0; n < 5; ++n) {
            int i, j;
            if (half == 0) { i = pg; j = 5 + n; } else { i = 5 + pg; j = n; }
            const unsigned* ur  = hX + (s * 10 + i) * 17;
            const unsigned* vrw = hX + (s * 10 + j) * 17 + 8;
            float h1p[16];
            #pragma unroll
            for (int cc = 0; cc < 8; ++cc) {
                const unsigned uu = ur[cc], vv = vrw[cc];
                h1p[2 * cc]     = fmaxf(bf_lo(uu) + bf_lo(vv) + c_b1[2 * cc], 0.f);
                h1p[2 * cc + 1] = fmaxf(bf_hi(uu) + bf_hi(vv) + c_b1[2 * cc + 1], 0.f);
            }
            float a[16];
            #pragma unroll
            for (int o = 0; o < 16; ++o) a[o] = c_b2[o];
            #pragma unroll
            for (int k = 0; k < 16; ++k) {
                const float hk = h1p[k];
                const float* wr = c_w2 + k * 16;
                #pragma unroll
                for (int o = 0; o < 16; ++o) a[o] = fmaf(hk, wr[o], a[o]);
            }
            float c3[8];
            #pragma unroll
            for (int o = 0; o < 8; ++o) c3[o] = c_b3[o];
            #pragma unroll
            for (int k = 0; k < 16; ++k) {
                const float hk = fmaxf(a[k], 0.f);
                const float* wr = c_w3 + k * 8;
                #pragma unroll
                for (int o = 0; o < 8; ++o) c3[o] = fmaf(hk, wr[o], c3[o]);
            }
            pm0 = fmaxf(pm0, fmaxf(c3[0], c3[1]));
            pm1 = fmaxf(pm1, fmaxf(c3[2], c3[3]));
            pm2 = fmaxf(pm2, fmaxf(c3[4], c3[5]));
            pm3 = fmaxf(pm3, fmaxf(c3[6], c3[7]));
        }
        float* dst = sPm + ((s * 2 + half) * 5 + pg) * 4;
        dst[0] = pm0; dst[1] = pm1; dst[2] = pm2; dst[3] = pm3;
    }
    __syncthreads();

    // ===== Phase D: max over 5 groups -> g =====
    if (tid < vs * 8) {
        const int s = tid >> 3;
        const int r = tid & 7;
        const int half = r >> 2, m = r & 3;
        float mx = -1e30f;
        #pragma unroll
        for (int pg = 0; pg < 5; ++pg)
            mx = fmaxf(mx, sPm[((s * 2 + half) * 5 + pg) * 4 + m]);
        sG[s * 8 + r] = mx;
    }
    __syncthreads();

    // ===== Phase E1: team layer 1 (84 -> 64), 4 lanes/row =====
    if (tid < vs * 8) {
        const int s = tid >> 3;
        const int half = (tid >> 2) & 1;
        const int q = tid & 3;
        const int oq = q * 16;
        float a[16];
        #pragma unroll
        for (int o = 0; o < 16; ++o) a[o] = t_b1[oq + o];
        for (int h5 = 0; h5 < 5; ++h5) {
            const int row = s * 10 + half * 5 + h5;
            #pragma unroll
            for (int cc = 0; cc < 8; ++cc) {
                const unsigned hv = ho32[row * 9 + cc];
                const float x0 = bf_lo(hv), x1 = bf_hi(hv);
                const int k0 = h5 * 16 + 2 * cc;
                #pragma unroll
                for (int ob = 0; ob < 4; ++ob) {
                    const float4 w0 = *(const float4*)(t_w1 + k0 * 64 + oq + ob * 4);
                    const float4 w1 = *(const float4*)(t_w1 + (k0 + 1) * 64 + oq + ob * 4);
                    a[ob * 4 + 0] = fmaf(x0, w0.x, a[ob * 4 + 0]);
                    a[ob * 4 + 1] = fmaf(x0, w0.y, a[ob * 4 + 1]);
                    a[ob * 4 + 2] = fmaf(x0, w0.z, a[ob * 4 + 2]);
                    a[ob * 4 + 3] = fmaf(x0, w0.w, a[ob * 4 + 3]);
                    a[ob * 4 + 0] = fmaf(x1, w1.x, a[ob * 4 + 0]);
                    a[ob * 4 + 1] = fmaf(x1, w1.y, a[ob * 4 + 1]);
                    a[ob * 4 + 2] = fmaf(x1, w1.z, a[ob * 4 + 2]);
                    a[ob * 4 + 3] = fmaf(x1, w1.w, a[ob * 4 + 3]);
                }
            }
        }
        #pragma unroll
        for (int m = 0; m < 4; ++m) {
            const float gv = sG[s * 8 + half * 4 + m];
            #pragma unroll
            for (int ob = 0; ob < 4; ++ob) {
                const float4 w = *(const float4*)(t_w1 + (80 + m) * 64 + oq + ob * 4);
                a[ob * 4 + 0] = fmaf(gv, w.x, a[ob * 4 + 0]);
                a[ob * 4 + 1] = fmaf(gv, w.y, a[ob * 4 + 1]);
                a[ob * 4 + 2] = fmaf(gv, w.z, a[ob * 4 + 2]);
                a[ob * 4 + 3] = fmaf(gv, w.w, a[ob * 4 + 3]);
            }
        }
        const int row48 = s * 2 + half;
        #pragma unroll
        for (int cc = 0; cc < 8; ++cc)
            h1t[row48 * 33 + q * 8 + cc] =
                pack_bf(fmaxf(a[2 * cc], 0.f), fmaxf(a[2 * cc + 1], 0.f));
    }
    __syncthreads();

    // ===== Phase E2: team layer 2 (64 -> 64) =====
    if (tid < vs * 8) {
        const int s = tid >> 3;
        const int half = (tid >> 2) & 1;
        const int q = tid & 3;
        const int oq = q * 16;
        const int row48 = s * 2 + half;
        float a[16];
        #pragma unroll
        for (int o = 0; o < 16; ++o) a[o] = t_b2[oq + o];
        #pragma unroll 8
        for (int cc = 0; cc < 32; ++cc) {
            const unsigned hv = h1t[row48 * 33 + cc];
            const float x0 = bf_lo(hv), x1 = bf_hi(hv);
            #pragma unroll
            for (int ob = 0; ob < 4; ++ob) {
                const float4 w0 = *(const float4*)(t_w2 + (2 * cc) * 64 + oq + ob * 4);
                const float4 w1 = *(const float4*)(t_w2 + (2 * cc + 1) * 64 + oq + ob * 4);
                a[ob * 4 + 0] = fmaf(x0, w0.x, a[ob * 4 + 0]);
                a[ob * 4 + 1] = fmaf(x0, w0.y, a[ob * 4 + 1]);
                a[ob * 4 + 2] = fmaf(x0, w0.z, a[ob * 4 + 2]);
                a[ob * 4 + 3] = fmaf(x0, w0.w, a[ob * 4 + 3]);
                a[ob * 4 + 0] = fmaf(x1, w1.x, a[ob * 4 + 0]);
                a[ob * 4 + 1] = fmaf(x1, w1.y, a[ob * 4 + 1]);
                a[ob * 4 + 2] = fmaf(x1, w1.z, a[ob * 4 + 2]);
                a[ob * 4 + 3] = fmaf(x1, w1.w, a[ob * 4 + 3]);
            }
        }
        #pragma unroll
        for (int cc = 0; cc < 8; ++cc)
            h2t[row48 * 33 + q * 8 + cc] =
                pack_bf(fmaxf(a[2 * cc], 0.f), fmaxf(a[2 * cc + 1], 0.f));
    }
    __syncthreads();

    // ===== Phase E3: team layer 3 (64 -> 16, linear) =====
    if (tid < vs * 8) {
        const int s = tid >> 3;
        const int half = (tid >> 2) & 1;
        const int q = tid & 3;
        const int oq = q * 4;
        const int row48 = s * 2 + half;
        float a0s = t_b3[oq], a1s = t_b3[oq + 1], a2s = t_b3[oq + 2], a3s = t_b3[oq + 3];
        #pragma unroll 8
        for (int cc = 0; cc < 32; ++cc) {
            const unsigned hv = h2t[row48 * 33 + cc];
            const float x0 = bf_lo(hv), x1 = bf_hi(hv);
            const float4 w0 = *(const float4*)(t_w3 + (2 * cc) * 16 + oq);
            const float4 w1 = *(const float4*)(t_w3 + (2 * cc + 1) * 16 + oq);
            a0s = fmaf(x0, w0.x, a0s); a1s = fmaf(x0, w0.y, a1s);
            a2s = fmaf(x0, w0.z, a2s); a3s = fmaf(x0, w0.w, a3s);
            a0s = fmaf(x1, w1.x, a0s); a1s = fmaf(x1, w1.y, a1s);
            a2s = fmaf(x1, w1.z, a2s); a3s = fmaf(x1, w1.w, a3s);
        }
        float* dst = sT + s * 33 + half * 16 + oq;
        dst[0] = a0s; dst[1] = a1s; dst[2] = a2s; dst[3] = a3s;
    }
    __syncthreads();

    // ===== Phase F: final MLP (32->16->16->2) + softmax, 1 lane/sample =====
    if (tid < vs) {
        const float* tr = sT + tid * 33;
        float g1[16];
        #pragma unroll
        for (int o = 0; o < 16; ++o) g1[o] = f_b1[o];
        #pragma unroll
        for (int k = 0; k < 32; ++k) {
            const float hk = tr[k];
            const float* wr = f_w1 + k * 16;
            #pragma unroll
            for (int o = 0; o < 16; ++o) g1[o] = fmaf(hk, wr[o], g1[o]);
        }
        float g2[16];
        #pragma unroll
        for (int o = 0; o < 16; ++o) g2[o] = f_b2[o];
        #pragma unroll
        for (int k = 0; k < 16; ++k) {
            const float hk = fmaxf(g1[k], 0.f);
            const float* wr = f_w2 + k * 16;
            #pragma unroll
            for (int o = 0; o < 16; ++o) g2[o] = fmaf(hk, wr[o], g2[o]);
        }
        float l0 = f_b3[0], l1 = f_b3[1];
        #pragma unroll
        for (int k = 0; k < 16; ++k) {
            const float hk = fmaxf(g2[k], 0.f);
            l0 = fmaf(hk, f_w3[2 * k], l0);
            l1 = fmaf(hk, f_w3[2 * k + 1], l1);
        }
        const float e = expf(l1 - l0);
        const float p0 = 1.f / (1.f + e);
        out[(size_t)(s0 + tid) * 2]     = p0;
        out[(size_t)(s0 + tid) * 2 + 1] = 1.f - p0;
    }
}

extern "C" void kernel_launch(void* const* d_in, const int* in_sizes, int n_in,
                              void* d_out, int out_size, void* d_ws, size_t ws_size,
                              hipStream_t stream) {
    (void)in_sizes; (void)n_in; (void)d_ws; (void)ws_size; (void)out_size;
    const float* x    = (const float*)d_in[0];
    const float* h_w1 = (const float*)d_in[1];  const float* h_b1 = (const float*)d_in[2];
    const float* h_w2 = (const float*)d_in[3];  const float* h_b2 = (const float*)d_in[4];
    const float* h_w3 = (const float*)d_in[5];  const float* h_b3 = (const float*)d_in[6];
    const float* c_w1 = (const float*)d_in[7];  const float* c_b1 = (const float*)d_in[8];
    const float* c_w2 = (const float*)d_in[9];  const float* c_b2 = (const float*)d_in[10];
    const float* c_w3 = (const float*)d_in[11]; const float* c_b3 = (const float*)d_in[12];
    const float* t_w1 = (const float*)d_in[13]; const float* t_b1 = (const float*)d_in[14];
    const float* t_w2 = (const float*)d_in[15]; const float* t_b2 = (const float*)d_in[16];
    const float* t_w3 = (const float*)d_in[17]; const float* t_b3 = (const float*)d_in[18];
    const float* f_w1 = (const float*)d_in[19]; const float* f_b1 = (const float*)d_in[20];
    const float* f_w2 = (const float*)d_in[21]; const float* f_b2 = (const float*)d_in[22];
    const float* f_w3 = (const float*)d_in[23]; const float* f_b3 = (const float*)d_in[24];
    float* out = (float*)d_out;

    const int grid = (NB + SPB - 1) / SPB;   // 2731 workgroups
    fused_model_kernel<<<grid, THREADS, 0, stream>>>(
        x, h_w1, h_b1, h_w2, h_b2, h_w3, h_b3,
        c_w1, c_b1, c_w2, c_b2, c_w3, c_b3,
        t_w1, t_b1, t_w2, t_b2, t_w3, t_b3,
        f_w1, f_b1, f_w2, f_b2, f_w3, f_b3,
        out);
}

// Round 13
// 426.760 us; speedup vs baseline: 1.2699x; 1.0797x over previous
//
#include <hip/hip_runtime.h>
#include <hip/hip_bf16.h>
#include <math.h>

// Round 13: full-MFMA hero chain + spill fix.
//  r12: L1 MFMA passed (461us) but wf[5][2] preload spilled (WRITE 73MB,
//  VGPR 64) and phases B (2048-FMA/lane serial VALU) remained.
//  Changes: (a) JIT B-frags per K-chunk in a ROLLED c-loop (no spill);
//  (b) L2/L3/uv as chained MFMA layers, in-place LDS activations with
//  read-frags -> barrier -> mfma -> write-D -> barrier. C-F verbatim r12.

#define THREADS 256
#define SPB 24
#define NB 65536

typedef __attribute__((ext_vector_type(8))) short short8;   // 8 bf16
typedef __attribute__((ext_vector_type(4))) float f32x4;    // 4 f32

__device__ __forceinline__ unsigned bfr(float f) {
    unsigned u = __float_as_uint(f);
    return (u + 0x7fffu + ((u >> 16) & 1u)) >> 16;   // RNE to bf16
}
__device__ __forceinline__ unsigned pack_bf(float a, float b) {
    return bfr(a) | (bfr(b) << 16);
}
__device__ __forceinline__ float bf_lo(unsigned u) { return __uint_as_float(u << 16); }
__device__ __forceinline__ float bf_hi(unsigned u) { return __uint_as_float(u & 0xffff0000u); }

__global__ __launch_bounds__(THREADS, 4) void fused_model_kernel(
    const float* __restrict__ x,
    const float* __restrict__ h_w1, const float* __restrict__ h_b1,
    const float* __restrict__ h_w2, const float* __restrict__ h_b2,
    const float* __restrict__ h_w3, const float* __restrict__ h_b3,
    const float* __restrict__ c_w1, const float* __restrict__ c_b1,
    const float* __restrict__ c_w2, const float* __restrict__ c_b2,
    const float* __restrict__ c_w3, const float* __restrict__ c_b3,
    const float* __restrict__ t_w1, const float* __restrict__ t_b1,
    const float* __restrict__ t_w2, const float* __restrict__ t_b2,
    const float* __restrict__ t_w3, const float* __restrict__ t_b3,
    const float* __restrict__ f_w1, const float* __restrict__ f_b1,
    const float* __restrict__ f_w2, const float* __restrict__ f_b2,
    const float* __restrict__ f_w3, const float* __restrict__ f_b3,
    float* __restrict__ out)
{
    // LDS arena: 8112 u32 = 32448 B -> 4 wg/CU.
    //  [0,4800)    actsA: u16 [240][40] (x-stage / h1 / h2 / ho, in-place)
    //              alias: hX u32 [240][17] (uv rows, phase C)
    //              alias: h1t [0,1650), h2t [1650,3300) (E phases)
    //  [4800,6960) ho32: u16 [240][18] (== u32 [240][9], B..E1)
    //  [6960,7920) sPm f32 (C..D) / sT f32 24x33 (E3..F)
    //  [7920,8112) sG f32 24x8
    __shared__ unsigned smem_u[8112];
    unsigned short* const actsA = (unsigned short*)smem_u;
    unsigned* const hX    = smem_u;
    unsigned short* const hXu16 = (unsigned short*)smem_u;
    unsigned* const h1t   = smem_u;
    unsigned* const h2t   = smem_u + 1650;
    unsigned* const ho32  = smem_u + 4800;
    unsigned short* const hoU16 = (unsigned short*)(smem_u + 4800);
    float*    const sPm   = (float*)(smem_u + 6960);
    float*    const sT    = (float*)(smem_u + 6960);
    float*    const sG    = (float*)(smem_u + 7920);

    const int tid = threadIdx.x;
    const int wg  = blockIdx.x;
    const int s0  = wg * SPB;
    const int vs  = (NB - s0 < SPB) ? (NB - s0) : SPB;
    const int vr  = vs * 10;

    const int lane = tid & 63;
    const int wv   = tid >> 6;        // wave 0..3
    const int lm   = lane & 15;
    const int lg   = lane >> 4;

    const short8 zero8 = (short8){0,0,0,0,0,0,0,0};

    // ===== L1: [240x140]@[140x32] MFMA, rolled K-chunks, JIT B-frags =====
    f32x4 acc[4][2];
    #pragma unroll
    for (int t = 0; t < 4; ++t) {
        const float b0 = h_b1[lm], b1 = h_b1[16 + lm];
        acc[t][0] = (f32x4){b0, b0, b0, b0};
        acc[t][1] = (f32x4){b1, b1, b1, b1};
    }
    for (int c = 0; c < 5; ++c) {     // rolled: acc static-indexed inside
        short8 w0f, w1f;
        #pragma unroll
        for (int i = 0; i < 8; ++i) {
            const int k = c * 32 + lg * 8 + i;
            w0f[i] = (short)((k < 140) ? bfr(h_w1[k * 32 + lm]) : 0);
            w1f[i] = (short)((k < 140) ? bfr(h_w1[k * 32 + 16 + lm]) : 0);
        }
        for (int j = tid; j < vr * 8; j += THREADS) {
            const int row = j >> 3, q = j & 7;
            unsigned lo = 0, hi = 0;
            if (c < 4 || q < 3) {
                const float4 v = *(const float4*)(
                    x + ((size_t)s0 * 10 + row) * 140 + c * 32 + q * 4);
                lo = pack_bf(v.x, v.y);
                hi = pack_bf(v.z, v.w);
            }
            smem_u[row * 20 + q * 2]     = lo;
            smem_u[row * 20 + q * 2 + 1] = hi;
        }
        __syncthreads();
        #pragma unroll
        for (int t = 0; t < 4; ++t) {
            const int tl = wv + 4 * t;
            if (tl < 15) {
                const short8 af = *(const short8*)(actsA + (tl * 16 + lm) * 40 + lg * 8);
                acc[t][0] = __builtin_amdgcn_mfma_f32_16x16x32_bf16(af, w0f, acc[t][0], 0, 0, 0);
                acc[t][1] = __builtin_amdgcn_mfma_f32_16x16x32_bf16(af, w1f, acc[t][1], 0, 0, 0);
            }
        }
        __syncthreads();
    }
    // h1 = relu -> actsA [240][40] cols 0..31 (D: col=lm, row=lg*4+r)
    #pragma unroll
    for (int t = 0; t < 4; ++t) {
        const int tl = wv + 4 * t;
        if (tl < 15) {
            #pragma unroll
            for (int nt = 0; nt < 2; ++nt)
                #pragma unroll
                for (int r = 0; r < 4; ++r)
                    actsA[(tl * 16 + lg * 4 + r) * 40 + nt * 16 + lm] =
                        (unsigned short)bfr(fmaxf(acc[t][nt][r], 0.f));
        }
    }
    __syncthreads();

    // ===== L2: [240x32]@[32x32] MFMA, in-place =====
    {
        short8 af[4];
        #pragma unroll
        for (int t = 0; t < 4; ++t) {
            const int tl = wv + 4 * t;
            af[t] = (tl < 15) ? *(const short8*)(actsA + (tl * 16 + lm) * 40 + lg * 8) : zero8;
        }
        short8 w0f, w1f;
        #pragma unroll
        for (int i = 0; i < 8; ++i) {
            const int k = lg * 8 + i;
            w0f[i] = (short)bfr(h_w2[k * 32 + lm]);
            w1f[i] = (short)bfr(h_w2[k * 32 + 16 + lm]);
        }
        __syncthreads();              // all h1 reads done before overwrite
        f32x4 a2[4][2];
        #pragma unroll
        for (int t = 0; t < 4; ++t) {
            const float b0 = h_b2[lm], b1 = h_b2[16 + lm];
            a2[t][0] = (f32x4){b0, b0, b0, b0};
            a2[t][1] = (f32x4){b1, b1, b1, b1};
            const int tl = wv + 4 * t;
            if (tl < 15) {
                a2[t][0] = __builtin_amdgcn_mfma_f32_16x16x32_bf16(af[t], w0f, a2[t][0], 0, 0, 0);
                a2[t][1] = __builtin_amdgcn_mfma_f32_16x16x32_bf16(af[t], w1f, a2[t][1], 0, 0, 0);
                #pragma unroll
                for (int nt = 0; nt < 2; ++nt)
                    #pragma unroll
                    for (int r = 0; r < 4; ++r)
                        actsA[(tl * 16 + lg * 4 + r) * 40 + nt * 16 + lm] =
                            (unsigned short)bfr(fmaxf(a2[t][nt][r], 0.f));
            }
        }
        __syncthreads();
    }

    // ===== L3: [240x32]@[32x16] MFMA (linear) -> ho =====
    {
        short8 af[4];
        #pragma unroll
        for (int t = 0; t < 4; ++t) {
            const int tl = wv + 4 * t;
            af[t] = (tl < 15) ? *(const short8*)(actsA + (tl * 16 + lm) * 40 + lg * 8) : zero8;
        }
        short8 w3f;
        #pragma unroll
        for (int i = 0; i < 8; ++i) {
            const int k = lg * 8 + i;
            w3f[i] = (short)bfr(h_w3[k * 16 + lm]);
        }
        __syncthreads();
        #pragma unroll
        for (int t = 0; t < 4; ++t) {
            const float b = h_b3[lm];
            f32x4 a3 = (f32x4){b, b, b, b};
            const int tl = wv + 4 * t;
            if (tl < 15) {
                a3 = __builtin_amdgcn_mfma_f32_16x16x32_bf16(af[t], w3f, a3, 0, 0, 0);
                #pragma unroll
                for (int r = 0; r < 4; ++r) {
                    const int row = tl * 16 + lg * 4 + r;
                    const unsigned short hb = (unsigned short)bfr(a3[r]);
                    hoU16[row * 18 + lm]  = hb;     // for E1
                    actsA[row * 40 + lm]  = hb;     // for uv A-frags
                }
            }
        }
        __syncthreads();
    }

    // ===== uv: [240x16]@[16x32] MFMA (K zero-padded to 32) =====
    {
        short8 af[4];
        #pragma unroll
        for (int t = 0; t < 4; ++t) {
            const int tl = wv + 4 * t;
            af[t] = (tl < 15 && lg < 2)
                ? *(const short8*)(actsA + (tl * 16 + lm) * 40 + lg * 8) : zero8;
        }
        short8 wuf, wvf;
        #pragma unroll
        for (int i = 0; i < 8; ++i) {
            const int k = lg * 8 + i;
            wuf[i] = (short)((k < 16) ? bfr(c_w1[k * 16 + lm]) : 0);
            wvf[i] = (short)((k < 16) ? bfr(c_w1[(16 + k) * 16 + lm]) : 0);
        }
        __syncthreads();              // ho reads done before hX overwrite
        #pragma unroll
        for (int t = 0; t < 4; ++t) {
            f32x4 au = (f32x4){0.f, 0.f, 0.f, 0.f};
            f32x4 av = (f32x4){0.f, 0.f, 0.f, 0.f};
            const int tl = wv + 4 * t;
            if (tl < 15) {
                au = __builtin_amdgcn_mfma_f32_16x16x32_bf16(af[t], wuf, au, 0, 0, 0);
                av = __builtin_amdgcn_mfma_f32_16x16x32_bf16(af[t], wvf, av, 0, 0, 0);
                #pragma unroll
                for (int r = 0; r < 4; ++r) {
                    const int row = tl * 16 + lg * 4 + r;
                    hXu16[row * 34 + lm]      = (unsigned short)bfr(au[r]);
                    hXu16[row * 34 + 16 + lm] = (unsigned short)bfr(av[r]);
                }
            }
        }
        __syncthreads();
    }

    // ===== Phase C: 50 pairs/sample, counter L2/L3 + pool2 =====
    if (tid < vs * 10) {
        const int s = tid / 10;
        const int t10 = tid % 10;
        const int half = t10 / 5;
        const int pg = t10 % 5;
        float pm0 = -1e30f, pm1 = -1e30f, pm2 = -1e30f, pm3 = -1e30f;
        for (int n = 0; n < 5; ++n) {
            int i, j;
            if (half == 0) { i = pg; j = 5 + n; } else { i = 5 + pg; j = n; }
            const unsigned* ur  = hX + (s * 10 + i) * 17;
            const unsigned* vrw = hX + (s * 10 + j) * 17 + 8;
            float h1p[16];
            #pragma unroll
            for (int cc = 0; cc < 8; ++cc) {
                const unsigned uu = ur[cc], vv = vrw[cc];
                h1p[2 * cc]     = fmaxf(bf_lo(uu) + bf_lo(vv) + c_b1[2 * cc], 0.f);
                h1p[2 * cc + 1] = fmaxf(bf_hi(uu) + bf_hi(vv) + c_b1[2 * cc + 1], 0.f);
            }
            float a[16];
            #pragma unroll
            for (int o = 0; o < 16; ++o) a[o] = c_b2[o];
            #pragma unroll
            for (int k = 0; k < 16; ++k) {
                const float hk = h1p[k];
                const float* wr = c_w2 + k * 16;
                #pragma unroll
                for (int o = 0; o < 16; ++o) a[o] = fmaf(hk, wr[o], a[o]);
            }
            float c3[8];
            #pragma unroll
            for (int o = 0; o < 8; ++o) c3[o] = c_b3[o];
            #pragma unroll
            for (int k = 0; k < 16; ++k) {
                const float hk = fmaxf(a[k], 0.f);
                const float* wr = c_w3 + k * 8;
                #pragma unroll
                for (int o = 0; o < 8; ++o) c3[o] = fmaf(hk, wr[o], c3[o]);
            }
            pm0 = fmaxf(pm0, fmaxf(c3[0], c3[1]));
            pm1 = fmaxf(pm1, fmaxf(c3[2], c3[3]));
            pm2 = fmaxf(pm2, fmaxf(c3[4], c3[5]));
            pm3 = fmaxf(pm3, fmaxf(c3[6], c3[7]));
        }
        float* dst = sPm + ((s * 2 + half) * 5 + pg) * 4;
        dst[0] = pm0; dst[1] = pm1; dst[2] = pm2; dst[3] = pm3;
    }
    __syncthreads();

    // ===== Phase D: max over 5 groups -> g =====
    if (tid < vs * 8) {
        const int s = tid >> 3;
        const int r = tid & 7;
        const int half = r >> 2, m = r & 3;
        float mx = -1e30f;
        #pragma unroll
        for (int pg = 0; pg < 5; ++pg)
            mx = fmaxf(mx, sPm[((s * 2 + half) * 5 + pg) * 4 + m]);
        sG[s * 8 + r] = mx;
    }
    __syncthreads();

    // ===== Phase E1: team layer 1 (84 -> 64), 4 lanes/row =====
    if (tid < vs * 8) {
        const int s = tid >> 3;
        const int half = (tid >> 2) & 1;
        const int q = tid & 3;
        const int oq = q * 16;
        float a[16];
        #pragma unroll
        for (int o = 0; o < 16; ++o) a[o] = t_b1[oq + o];
        for (int h5 = 0; h5 < 5; ++h5) {
            const int row = s * 10 + half * 5 + h5;
            #pragma unroll
            for (int cc = 0; cc < 8; ++cc) {
                const unsigned hv = ho32[row * 9 + cc];
                const float x0 = bf_lo(hv), x1 = bf_hi(hv);
                const int k0 = h5 * 16 + 2 * cc;
                #pragma unroll
                for (int ob = 0; ob < 4; ++ob) {
                    const float4 w0 = *(const float4*)(t_w1 + k0 * 64 + oq + ob * 4);
                    const float4 w1 = *(const float4*)(t_w1 + (k0 + 1) * 64 + oq + ob * 4);
                    a[ob * 4 + 0] = fmaf(x0, w0.x, a[ob * 4 + 0]);
                    a[ob * 4 + 1] = fmaf(x0, w0.y, a[ob * 4 + 1]);
                    a[ob * 4 + 2] = fmaf(x0, w0.z, a[ob * 4 + 2]);
                    a[ob * 4 + 3] = fmaf(x0, w0.w, a[ob * 4 + 3]);
                    a[ob * 4 + 0] = fmaf(x1, w1.x, a[ob * 4 + 0]);
                    a[ob * 4 + 1] = fmaf(x1, w1.y, a[ob * 4 + 1]);
                    a[ob * 4 + 2] = fmaf(x1, w1.z, a[ob * 4 + 2]);
                    a[ob * 4 + 3] = fmaf(x1, w1.w, a[ob * 4 + 3]);
                }
            }
        }
        #pragma unroll
        for (int m = 0; m < 4; ++m) {
            const float gv = sG[s * 8 + half * 4 + m];
            #pragma unroll
            for (int ob = 0; ob < 4; ++ob) {
                const float4 w = *(const float4*)(t_w1 + (80 + m) * 64 + oq + ob * 4);
                a[ob * 4 + 0] = fmaf(gv, w.x, a[ob * 4 + 0]);
                a[ob * 4 + 1] = fmaf(gv, w.y, a[ob * 4 + 1]);
                a[ob * 4 + 2] = fmaf(gv, w.z, a[ob * 4 + 2]);
                a[ob * 4 + 3] = fmaf(gv, w.w, a[ob * 4 + 3]);
            }
        }
        const int row48 = s * 2 + half;
        #pragma unroll
        for (int cc = 0; cc < 8; ++cc)
            h1t[row48 * 33 + q * 8 + cc] =
                pack_bf(fmaxf(a[2 * cc], 0.f), fmaxf(a[2 * cc + 1], 0.f));
    }
    __syncthreads();

    // ===== Phase E2: team layer 2 (64 -> 64) =====
    if (tid < vs * 8) {
        const int s = tid >> 3;
        const int half = (tid >> 2) & 1;
        const int q = tid & 3;
        const int oq = q * 16;
        const int row48 = s * 2 + half;
        float a[16];
        #pragma unroll
        for (int o = 0; o < 16; ++o) a[o] = t_b2[oq + o];
        #pragma unroll 8
        for (int cc = 0; cc < 32; ++cc) {
            const unsigned hv = h1t[row48 * 33 + cc];
            const float x0 = bf_lo(hv), x1 = bf_hi(hv);
            #pragma unroll
            for (int ob = 0; ob < 4; ++ob) {
                const float4 w0 = *(const float4*)(t_w2 + (2 * cc) * 64 + oq + ob * 4);
                const float4 w1 = *(const float4*)(t_w2 + (2 * cc + 1) * 64 + oq + ob * 4);
                a[ob * 4 + 0] = fmaf(x0, w0.x, a[ob * 4 + 0]);
                a[ob * 4 + 1] = fmaf(x0, w0.y, a[ob * 4 + 1]);
                a[ob * 4 + 2] = fmaf(x0, w0.z, a[ob * 4 + 2]);
                a[ob * 4 + 3] = fmaf(x0, w0.w, a[ob * 4 + 3]);
                a[ob * 4 + 0] = fmaf(x1, w1.x, a[ob * 4 + 0]);
                a[ob * 4 + 1] = fmaf(x1, w1.y, a[ob * 4 + 1]);
                a[ob * 4 + 2] = fmaf(x1, w1.z, a[ob * 4 + 2]);
                a[ob * 4 + 3] = fmaf(x1, w1.w, a[ob * 4 + 3]);
            }
        }
        #pragma unroll
        for (int cc = 0; cc < 8; ++cc)
            h2t[row48 * 33 + q * 8 + cc] =
                pack_bf(fmaxf(a[2 * cc], 0.f), fmaxf(a[2 * cc + 1], 0.f));
    }
    __syncthreads();

    // ===== Phase E3: team layer 3 (64 -> 16, linear) =====
    if (tid < vs * 8) {
        const int s = tid >> 3;
        const int half = (tid >> 2) & 1;
        const int q = tid & 3;
        const int oq = q * 4;
        const int row48 = s * 2 + half;
        float a0s = t_b3[oq], a1s = t_b3[oq + 1], a2s = t_b3[oq + 2], a3s = t_b3[oq + 3];
        #pragma unroll 8
        for (int cc = 0; cc < 32; ++cc) {
            const unsigned hv = h2t[row48 * 33 + cc];
            const float x0 = bf_lo(hv), x1 = bf_hi(hv);
            const float4 w0 = *(const float4*)(t_w3 + (2 * cc) * 16 + oq);
            const float4 w1 = *(const float4*)(t_w3 + (2 * cc + 1) * 16 + oq);
            a0s = fmaf(x0, w0.x, a0s); a1s = fmaf(x0, w0.y, a1s);
            a2s = fmaf(x0, w0.z, a2s); a3s = fmaf(x0, w0.w, a3s);
            a0s = fmaf(x1, w1.x, a0s); a1s = fmaf(x1, w1.y, a1s);
            a2s = fmaf(x1, w1.z, a2s); a3s = fmaf(x1, w1.w, a3s);
        }
        float* dst = sT + s * 33 + half * 16 + oq;
        dst[0] = a0s; dst[1] = a1s; dst[2] = a2s; dst[3] = a3s;
    }
    __syncthreads();

    // ===== Phase F: final MLP (32->16->16->2) + softmax, 1 lane/sample =====
    if (tid < vs) {
        const float* tr = sT + tid * 33;
        float g1[16];
        #pragma unroll
        for (int o = 0; o < 16; ++o) g1[o] = f_b1[o];
        #pragma unroll
        for (int k = 0; k < 32; ++k) {
            const float hk = tr[k];
            const float* wr = f_w1 + k * 16;
            #pragma unroll
            for (int o = 0; o < 16; ++o) g1[o] = fmaf(hk, wr[o], g1[o]);
        }
        float g2[16];
        #pragma unroll
        for (int o = 0; o < 16; ++o) g2[o] = f_b2[o];
        #pragma unroll
        for (int k = 0; k < 16; ++k) {
            const float hk = fmaxf(g1[k], 0.f);
            const float* wr = f_w2 + k * 16;
            #pragma unroll
            for (int o = 0; o < 16; ++o) g2[o] = fmaf(hk, wr[o], g2[o]);
        }
        float l0 = f_b3[0], l1 = f_b3[1];
        #pragma unroll
        for (int k = 0; k < 16; ++k) {
            const float hk = fmaxf(g2[k], 0.f);
            l0 = fmaf(hk, f_w3[2 * k], l0);
            l1 = fmaf(hk, f_w3[2 * k + 1], l1);
        }
        const float e = expf(l1 - l0);
        const float p0 = 1.f / (1.f + e);
        out[(size_t)(s0 + tid) * 2]     = p0;
        out[(size_t)(s0 + tid) * 2 + 1] = 1.f - p0;
    }
}

extern "C" void kernel_launch(void* const* d_in, const int* in_sizes, int n_in,
                              void* d_out, int out_size, void* d_ws, size_t ws_size,
                              hipStream_t stream) {
    (void)in_sizes; (void)n_in; (void)d_ws; (void)ws_size; (void)out_size;
    const float* x    = (const float*)d_in[0];
    const float* h_w1 = (const float*)d_in[1];  const float* h_b1 = (const float*)d_in[2];
    const float* h_w2 = (const float*)d_in[3];  const float* h_b2 = (const float*)d_in[4];
    const float* h_w3 = (const float*)d_in[5];  const float* h_b3 = (const float*)d_in[6];
    const float* c_w1 = (const float*)d_in[7];  const float* c_b1 = (const float*)d_in[8];
    const float* c_w2 = (const float*)d_in[9];  const float* c_b2 = (const float*)d_in[10];
    const float* c_w3 = (const float*)d_in[11]; const float* c_b3 = (const float*)d_in[12];
    const float* t_w1 = (const float*)d_in[13]; const float* t_b1 = (const float*)d_in[14];
    const float* t_w2 = (const float*)d_in[15]; const float* t_b2 = (const float*)d_in[16];
    const float* t_w3 = (const float*)d_in[17]; const float* t_b3 = (const float*)d_in[18];
    const float* f_w1 = (const float*)d_in[19]; const float* f_b1 = (const float*)d_in[20];
    const float* f_w2 = (const float*)d_in[21]; const float* f_b2 = (const float*)d_in[22];
    const float* f_w3 = (const float*)d_in[23]; const float* f_b3 = (const float*)d_in[24];
    float* out = (float*)d_out;

    const int grid = (NB + SPB - 1) / SPB;   // 2731 workgroups
    fused_model_kernel<<<grid, THREADS, 0, stream>>>(
        x, h_w1, h_b1, h_w2, h_b2, h_w3, h_b3,
        c_w1, c_b1, c_w2, c_b2, c_w3, c_b3,
        t_w1, t_b1, t_w2, t_b2, t_w3, t_b3,
        f_w1, f_b1, f_w2, f_b2, f_w3, f_b3,
        out);
}